// Round 11
// baseline (102.924 us; speedup 1.0000x reference)
//
#include <hip/hip_runtime.h>
#include <math.h>

#define NU 512
#define NCH 8192
#define CPB 32              // chains per block
#define NBLK 256            // 1 block/CU (96KB LDS)

typedef int i4 __attribute__((ext_vector_type(4)));
typedef float f2 __attribute__((ext_vector_type(2)));
typedef float f4 __attribute__((ext_vector_type(4)));

// R11 = R10 skeleton with the load schedule FIXED:
//  * R10 bug: LOADS issued at END of phase p, waited with vmcnt(0) right
//    after the next barrier -> one full burst-drain latency exposed PER PHASE
//    (measured 15.3K cy/phase vs ~2.4K work).
//  * Fix: hoist LOADS to right after WRITES (full phase ahead of their use),
//    counted vmcnt(4) (only the 4 z-stores are issued after the 8 target
//    loads; in-order retirement makes vmcnt(4) a proof the loads are done).
//  * A/B register sets alternate by phase parity: the hoisted loads write
//    the OTHER set than the one ds_writes just consumed; lgkm(0)+barrier
//    seals each set before its reload. Compute wave verbatim R9/R10.
__device__ __forceinline__ i4 mksrd(const void* p) {
    i4 v;
    v.x = (int)(unsigned)(uintptr_t)p;
    v.y = (int)((unsigned)((uintptr_t)p >> 32) & 0xFFFFu);
    v.z = (int)0xFFFFFFFFu;        // bounds check off
    v.w = 0x00020000;              // raw dword SRD
    return v;
}

__global__ __launch_bounds__(320, 1)
void reshopf_kernel(const float* __restrict__ Xr, const float* __restrict__ Xi,
                    const float* __restrict__ r0, const float* __restrict__ phi0,
                    const float* __restrict__ omegas,
                    float* __restrict__ zr, float* __restrict__ r_f,
                    float* __restrict__ phi_f)
{
    __shared__ float lds[24576];   // [R in: 0..32KB) [I in: 32..64KB) [z: 64..96KB)
    const int tid   = (int)threadIdx.x;
    const int lane  = tid & 63;
    const int wid   = __builtin_amdgcn_readfirstlane(tid >> 6);   // 0..4, uniform
    const int cbase = (int)blockIdx.x * CPB;
    const unsigned ldsb = (unsigned)(uintptr_t)&lds[0];

    if (wid < 4) {
        // ===================== LSU waves (dwordx4) =====================
        // lane l: row = l>>3 (8 rows/inst), chains 4*(l&7) (16B)
        const unsigned voff = ((unsigned)(lane >> 3)) * 32768u
                            + ((unsigned)(lane & 7)) * 16u;
        const i4 srdR = mksrd(Xr + cbase);
        const i4 srdI = mksrd(Xi + cbase);
        const i4 srdZ = mksrd(zr + cbase);
        const unsigned wl = ldsb + (unsigned)wid * 4096u
                          + ((unsigned)(lane >> 3)) * 128u
                          + ((unsigned)(lane & 7)) * 16u;

        f4 aR[4], aI[4], bR[4], bI[4], zv[4];   // static-indexed only

#define LD4(dst, srd, so) asm volatile("buffer_load_dwordx4 %0, %1, %2, %3 offen" \
        : "=v"(dst) : "v"(voff), "s"(srd), "s"(so))
#define LOADS(X, baseRow) { \
        const unsigned s0_ = ((unsigned)(baseRow) + (unsigned)wid * 32u) * 32768u; \
        LD4(X##R[0], srdR, s0_);            LD4(X##R[1], srdR, s0_ + 262144u); \
        LD4(X##R[2], srdR, s0_ + 524288u);  LD4(X##R[3], srdR, s0_ + 786432u); \
        LD4(X##I[0], srdI, s0_);            LD4(X##I[1], srdI, s0_ + 262144u); \
        LD4(X##I[2], srdI, s0_ + 524288u);  LD4(X##I[3], srdI, s0_ + 786432u); }

#define WRITES(X, HP) { const unsigned a_ = wl + (HP); \
        asm volatile("ds_write_b128 %0, %1 offset:0"     :: "v"(a_), "v"(X##R[0])); \
        asm volatile("ds_write_b128 %0, %1 offset:1024"  :: "v"(a_), "v"(X##R[1])); \
        asm volatile("ds_write_b128 %0, %1 offset:2048"  :: "v"(a_), "v"(X##R[2])); \
        asm volatile("ds_write_b128 %0, %1 offset:3072"  :: "v"(a_), "v"(X##R[3])); \
        asm volatile("ds_write_b128 %0, %1 offset:32768" :: "v"(a_), "v"(X##I[0])); \
        asm volatile("ds_write_b128 %0, %1 offset:33792" :: "v"(a_), "v"(X##I[1])); \
        asm volatile("ds_write_b128 %0, %1 offset:34816" :: "v"(a_), "v"(X##I[2])); \
        asm volatile("ds_write_b128 %0, %1 offset:35840" :: "v"(a_), "v"(X##I[3])); }

#define ZREADS(HP) { const unsigned a_ = wl + 65536u + (HP); \
        asm volatile("ds_read_b128 %0, %1 offset:0"    : "=v"(zv[0]) : "v"(a_)); \
        asm volatile("ds_read_b128 %0, %1 offset:1024" : "=v"(zv[1]) : "v"(a_)); \
        asm volatile("ds_read_b128 %0, %1 offset:2048" : "=v"(zv[2]) : "v"(a_)); \
        asm volatile("ds_read_b128 %0, %1 offset:3072" : "=v"(zv[3]) : "v"(a_)); }

#define ZSTORES(baseRow) { \
        const unsigned s0_ = ((unsigned)(baseRow) + (unsigned)wid * 32u) * 32768u; \
        asm volatile("buffer_store_dwordx4 %0, %1, %2, %3 offen" \
            :: "v"(zv[0]), "v"(voff), "s"(srdZ), "s"(s0_) : "memory"); \
        asm volatile("buffer_store_dwordx4 %0, %1, %2, %3 offen" \
            :: "v"(zv[1]), "v"(voff), "s"(srdZ), "s"(s0_ + 262144u) : "memory"); \
        asm volatile("buffer_store_dwordx4 %0, %1, %2, %3 offen" \
            :: "v"(zv[2]), "v"(voff), "s"(srdZ), "s"(s0_ + 524288u) : "memory"); \
        asm volatile("buffer_store_dwordx4 %0, %1, %2, %3 offen" \
            :: "v"(zv[3]), "v"(voff), "s"(srdZ), "s"(s0_ + 786432u) : "memory"); }

#define WAITVM(N) asm volatile("s_waitcnt vmcnt(%0)" :: "n"(N) : "memory")
#define WAITLG    asm volatile("s_waitcnt lgkmcnt(0)" ::: "memory")
#define WAITEX    asm volatile("s_waitcnt expcnt(0)" ::: "memory")

        // P(-2): pre-issue BOTH halves
        LOADS(a, 0);
        LOADS(b, 128);
        __builtin_amdgcn_s_barrier();                              // #1
        // P(-1): write half0 from A (one-time fill stall)
        WAITVM(8);                                                 // A done, B may fly
        WRITES(a, 0u);
        WAITLG;
        __builtin_amdgcn_s_barrier();                              // #2

        // phase 0: write half1 from B; load A<-rows 256
        WAITVM(0);
        WRITES(b, 16384u);
        LOADS(a, 256);
        WAITLG;
        __builtin_amdgcn_s_barrier();                              // #3

        // phase 1: write half0 from A; load B<-384; store z(0)
        WAITVM(0);                                                 // only loads in queue
        WRITES(a, 0u);
        LOADS(b, 384);
        WAITEX;
        ZREADS(0u);
        WAITLG;
        ZSTORES(0);
        __builtin_amdgcn_s_barrier();                              // #4

        // phases 2..13: steady state, counted vmcnt(4)
        for (int pp = 1; pp < 7; ++pp) {
            // even p = 2pp: write B (parity 1); load A; store z(2pp-1)
            WAITVM(4);
            WRITES(b, 16384u);
            LOADS(a, (2 * pp + 2) * 128);
            WAITEX;
            ZREADS(16384u);
            WAITLG;
            ZSTORES((2 * pp - 1) * 128);
            __builtin_amdgcn_s_barrier();                          // #5,7,...
            // odd p = 2pp+1: write A (parity 0); load B; store z(2pp)
            WAITVM(4);
            WRITES(a, 0u);
            LOADS(b, (2 * pp + 3) * 128);
            WAITEX;
            ZREADS(0u);
            WAITLG;
            ZSTORES((2 * pp) * 128);
            __builtin_amdgcn_s_barrier();                          // #6,8,...
        }

        // phase 14: write half15 from B (loaded at p=13, rows 1920); no loads
        WAITVM(4);
        WRITES(b, 16384u);
        WAITEX;
        ZREADS(16384u);
        WAITLG;
        ZSTORES(13 * 128);
        __builtin_amdgcn_s_barrier();                              // #17
        // phase 15: no writes/loads; store z(14)
        WAITEX;
        ZREADS(0u);
        WAITLG;
        ZSTORES(14 * 128);
        __builtin_amdgcn_s_barrier();                              // #18
        // post: store z(15)
        WAITEX;
        ZREADS(16384u);
        WAITLG;
        ZSTORES(15 * 128);
    } else {
        // ===================== compute wave (verbatim R9/R10) =====================
        const int l   = lane & 31;            // lanes 32-63 duplicate 0-31
        const int gch = cbase + l;
        const float INV2PI = 0.15915494309189533577f;

        const float wo    = omegas[gch & (NU - 1)];
        const float sig   = 1.0f / (1.0f + __expf(-wo));
        const float a_rev = (sig * 19.5f + 0.5f) * 0.01f;
        const float Ca    = __builtin_amdgcn_cosf(a_rev);
        const float Sa    = __builtin_amdgcn_sinf(a_rev);

        float r        = r0[gch];
        const float p0 = phi0[gch];
        float s = __builtin_amdgcn_sinf(p0 * INV2PI);
        float c = __builtin_amdgcn_cosf(p0 * INV2PI);
        float acc = 0.0f;

        const unsigned vR = ldsb + (unsigned)l * 4u;
        const unsigned vI = vR + 32768u;
        const unsigned vZ = vR + 65536u;

        auto step = [&](float xr, float xi, float& zout) {
            const float kxi = xi * -0.05f;
            const float kxr = xr * 0.05f;
            const float eps = kxi * s;
            const float t1  = s * Ca;
            const float sA  = fmaf(c, Sa, t1);
            const float t2  = c * Ca;
            const float cA  = fmaf(-s, Sa, t2);
            const float rr  = r * r;
            const float g1  = fmaf(-rr, r, r);
            const float tr  = fmaf(kxr, c, r);
            r = fmaf(0.01f, g1, tr);
            s = fmaf(eps, cA, sA);
            c = fmaf(-eps, sA, cA);
            acc += eps;
            zout = r * c;
        };

#define RD(it, R01, R23, I01, I23) { \
        const unsigned so_ = ((unsigned)((it) & 63)) * 512u; \
        const unsigned aR_ = vR + so_, aI_ = vI + so_; \
        asm volatile("ds_read2_b32 %0, %1 offset0:0 offset1:32"  : "=v"(R01) : "v"(aR_)); \
        asm volatile("ds_read2_b32 %0, %1 offset0:64 offset1:96" : "=v"(R23) : "v"(aR_)); \
        asm volatile("ds_read2_b32 %0, %1 offset0:0 offset1:32"  : "=v"(I01) : "v"(aI_)); \
        asm volatile("ds_read2_b32 %0, %1 offset0:64 offset1:96" : "=v"(I23) : "v"(aI_)); }

#define COMP(it, R01, R23, I01, I23) { \
        float z0_, z1_, z2_, z3_; \
        step(R01.x, I01.x, z0_); step(R01.y, I01.y, z1_); \
        step(R23.x, I23.x, z2_); step(R23.y, I23.y, z3_); \
        const float m_ = fmaf(s, s, c * c); \
        const float n_ = fmaf(-0.5f, m_, 1.5f); \
        s *= n_; c *= n_; \
        const unsigned aZ_ = vZ + ((unsigned)((it) & 63)) * 512u; \
        asm volatile("ds_write2_b32 %0, %1, %2 offset0:0 offset1:32"  :: "v"(aZ_), "v"(z0_), "v"(z1_)); \
        asm volatile("ds_write2_b32 %0, %1, %2 offset0:64 offset1:96" :: "v"(aZ_), "v"(z2_), "v"(z3_)); }

#define W4 { asm volatile("s_waitcnt lgkmcnt(4)" ::: "memory"); __builtin_amdgcn_sched_barrier(0); }
#define W0 { asm volatile("s_waitcnt lgkmcnt(0)" ::: "memory"); __builtin_amdgcn_sched_barrier(0); }

        __builtin_amdgcn_s_barrier();                              // #1
        __builtin_amdgcn_s_barrier();                              // #2  (half0 sealed)

        f2 Ar01, Ar23, Ai01, Ai23, Br01, Br23, Bi01, Bi23;
        for (int p = 0; p < 16; ++p) {
            const int it0 = p * 32;
            RD(it0, Ar01, Ar23, Ai01, Ai23);
            for (int j = 0; j < 15; ++j) {
                const int k = it0 + 2 * j;
                RD(k + 1, Br01, Br23, Bi01, Bi23); W4; COMP(k,     Ar01, Ar23, Ai01, Ai23);
                RD(k + 2, Ar01, Ar23, Ai01, Ai23); W4; COMP(k + 1, Br01, Br23, Bi01, Bi23);
            }
            RD(it0 + 31, Br01, Br23, Bi01, Bi23); W4; COMP(it0 + 30, Ar01, Ar23, Ai01, Ai23);
            W0; COMP(it0 + 31, Br01, Br23, Bi01, Bi23);
            asm volatile("s_waitcnt lgkmcnt(0)" ::: "memory");     // z writes sealed
            __builtin_amdgcn_s_barrier();                          // #3..#18
        }

        if (lane < 32) {
            r_f[gch] = r;
            phi_f[gch] = (float)((double)p0
                         + (double)a_rev * 2048.0 * 6.283185307179586476925287
                         + (double)acc);
        }
    }
}

extern "C" void kernel_launch(void* const* d_in, const int* in_sizes, int n_in,
                              void* d_out, int out_size, void* d_ws, size_t ws_size,
                              hipStream_t stream) {
    const float* Xr   = (const float*)d_in[0];
    const float* Xi   = (const float*)d_in[1];
    const float* r0   = (const float*)d_in[2];
    const float* phi0 = (const float*)d_in[3];
    const float* om   = (const float*)d_in[4];

    float* out   = (float*)d_out;
    float* zrp   = out;                               // Re(z): T*NCH floats
    float* r_f   = out + (size_t)2048 * NCH;          // NCH floats
    float* phi_f = r_f + NCH;                         // NCH floats

    reshopf_kernel<<<NBLK, 320, 0, stream>>>(Xr, Xi, r0, phi0, om, zrp, r_f, phi_f);
}